// Round 6
// baseline (737.644 us; speedup 1.0000x reference)
//
#include <hip/hip_runtime.h>
#include <hip/hip_fp16.h>

#define BATCH   65536
#define IN_DIM  784      // = 49 * 16 fp32 chunks exactly
#define K2      1600     // S2 row stride in halves (200 chunks of [s4|s4])
#define KI      49       // K-iterations: 49 * 16 fp32 (= 32 fp16-k) covers 784
#define H_DIM   1024
#define C_DIM   10
#define CPAD    16       // padded output cols for MFMA
#define BROW    1032     // BW2h row stride in halves (+8: bank spread, 16B-aligned)
#define BN_EPS  1e-5f

typedef _Float16 half8 __attribute__((ext_vector_type(8)));
typedef float    f32x4 __attribute__((ext_vector_type(4)));

#if defined(__has_builtin)
#if __has_builtin(__builtin_amdgcn_global_load_lds)
#define HAVE_ASYNC 1
#endif
#endif
#ifndef HAVE_ASYNC
#define HAVE_ASYNC 0
#endif

// Stage 16B/lane from global into LDS. Async: dest slot = base + lane*16.
__device__ __forceinline__ void stage16(const void* g, void* ldsBase, int lane) {
#if HAVE_ASYNC
  __builtin_amdgcn_global_load_lds((const __attribute__((address_space(1))) void*)g,
                                   (__attribute__((address_space(3))) void*)ldsBase,
                                   16, 0, 0);
#else
  ((half8*)ldsBase)[lane] = *(const half8*)g;
#endif
}

__device__ __forceinline__ float signf(float v) {
  return (v > 0.f) ? 1.f : ((v < 0.f) ? -1.f : 0.f);   // jnp.sign semantics
}

// ---------------------------------------------------------------------------
// K2: weight prep.
//  Blocks 0..1023: alpha1[j]=mean|w1[j]|; S2[j] chunks q: [s(4q..4q+3)|same],
//     pairing with in-register x split [hi4|lo4].
//  Blocks 1024..1039: BW2h[c][k] = (fp16) mean|w2[c]| * sign(w2[c][k]);
//     rows 10..15 and pad cols [1024,1032) zeroed.
// ---------------------------------------------------------------------------
__global__ __launch_bounds__(256) void prep_w(const float* __restrict__ w1,
                                              const float* __restrict__ w2,
                                              float* __restrict__ alpha1,
                                              _Float16* __restrict__ S2,
                                              _Float16* __restrict__ BW2h) {
  __shared__ float red[4];
  const int tid = threadIdx.x, lane = tid & 63, wave = tid >> 6;
  const int j = blockIdx.x;
  if (j < H_DIM) {
    const float* wr = w1 + (long)j * IN_DIM;
    float s = 0.f;
    for (int k = tid; k < IN_DIM; k += 256) s += fabsf(wr[k]);
#pragma unroll
    for (int off = 32; off > 0; off >>= 1) s += __shfl_xor(s, off, 64);
    if (lane == 0) red[wave] = s;
    __syncthreads();
    if (tid == 0) alpha1[j] = (red[0] + red[1] + red[2] + red[3]) * (1.f / IN_DIM);
    _Float16* dr = S2 + (long)j * K2;
    for (int q = tid; q < 200; q += 256) {
      half8 o;
#pragma unroll
      for (int i = 0; i < 4; ++i) {
        const int k = q * 4 + i;
        const _Float16 sg = (_Float16)((k < IN_DIM) ? signf(wr[k]) : 0.f);
        o[i]     = sg;
        o[i + 4] = sg;
      }
      *(half8*)&dr[q * 8] = o;
    }
  } else {
    const int c = j - H_DIM;                  // 0..15
    float alpha = 0.f;
    if (c < C_DIM) {
      const float* wr = w2 + (long)c * H_DIM;
      float s = 0.f;
      for (int k = tid; k < H_DIM; k += 256) s += fabsf(wr[k]);
#pragma unroll
      for (int off = 32; off > 0; off >>= 1) s += __shfl_xor(s, off, 64);
      if (lane == 0) red[wave] = s;
      __syncthreads();
      alpha = (red[0] + red[1] + red[2] + red[3]) * (1.f / H_DIM);
    }
    for (int k = tid; k < BROW; k += 256) {
      float v = 0.f;
      if (c < C_DIM && k < H_DIM) v = alpha * signf(w2[(long)c * H_DIM + k]);
      BW2h[(long)c * BROW + k] = (_Float16)v;
    }
  }
}

// ---------------------------------------------------------------------------
// K3: GEMM1  H[b][j] = alpha1[j] * sum_k x[b][k]*sign(w1[j][k]) in fp16x2.
// R2: zero-conflict XOR swizzle (verified) + fused BN col-stats.
// R3: XCD-aware remap (verified: FETCH 849->185 MB). fp32 H store (R5's fp16
//     store regressed gemm1 336->394; 2B stores suspected — reverted).
// R6: split_x FUSED: A-tile stages RAW x fp32 (16B/lane, same swizzle — rows
//     are 4x16B chunks either way); hi/lo fp16 split done in-register between
//     ds_read and MFMA (4 fp32 -> [hi4|lo4] half8, matching S2's [s4|s4]).
//     X2 (210 MB write + 210 MB read) eliminated; K-loop 50->49 iters.
// ---------------------------------------------------------------------------
__global__ __launch_bounds__(256) void gemm1(const float* __restrict__ x,
                                             const _Float16* __restrict__ S2,
                                             const float* __restrict__ alpha1,
                                             float* __restrict__ H,
                                             float* __restrict__ colsum,
                                             float* __restrict__ colsumsq) {
  __shared__ float    As[128 * 16];   // 8 KB: 128 rows x 16 fp32 (4 chunks of 16B)
  __shared__ _Float16 Bs[128 * 32];   // 8 KB: 128 rows x 32 fp16 (4 chunks of 16B)
  const int tid  = threadIdx.x;
  const int lane = tid & 63;
  const int wave = tid >> 6;

  // XCD-aware remap: b%8 = XCD id on MI355X.
  const int b     = blockIdx.x;
  const int xcd   = b & 7;
  const int local = b >> 3;                 // 0..511
  const int m0 = (xcd * 64 + (local >> 3)) * 128;
  const int n0 = (local & 7) * 128;

  const int wm = (wave >> 1) * 64;
  const int wn = (wave & 1) * 64;

  // staging: swizzled source chunk per lane; dest slot = lane (async HW rule)
  const int  kcg  = (lane & 3) ^ ((lane >> 3) & 3);
  const long aRow = (long)(m0 + wave * 32 + (lane >> 2));
  const long bRow = (long)(n0 + wave * 32 + (lane >> 2));
  const float*    aG = x  + aRow * IN_DIM + kcg * 4;   // 16B fp32 chunk
  const _Float16* bG = S2 + bRow * K2 + kcg * 8;       // 16B fp16 chunk
  float*    aL  = &As[(wave * 32) * 16];
  float*    aL2 = aL + 16 * 16;
  _Float16* bL  = &Bs[(wave * 32) * 32];
  _Float16* bL2 = bL + 16 * 32;

  f32x4 acc[4][4] = {};
  const int fr  = lane & 15;
  const int kc  = lane >> 4;
  const int swz = kc ^ ((fr >> 1) & 3);
  const int abase = (wm >> 4) * 256 + fr * 16 + swz * 4;   // floats; window 16r*16f
  const int bbase = (wn >> 4) * 512 + fr * 32 + swz * 8;   // halves; window 16r*32h

  for (int ks = 0; ks < KI; ++ks) {
    __syncthreads();
    stage16(aG + ks * 16, aL, lane);
    stage16(aG + 16 * IN_DIM + ks * 16, aL2, lane);
    stage16(bG + ks * 32, bL, lane);
    stage16(bG + 16 * K2 + ks * 32, bL2, lane);
    __syncthreads();
    f32x4 ar[4];
    half8 bf[4];
#pragma unroll
    for (int i = 0; i < 4; ++i) ar[i] = *(const f32x4*)&As[abase + i * 256];
#pragma unroll
    for (int i = 0; i < 4; ++i) bf[i] = *(const half8*)&Bs[bbase + i * 512];
    half8 af[4];
#pragma unroll
    for (int i = 0; i < 4; ++i) {
#pragma unroll
      for (int jj = 0; jj < 4; ++jj) {
        const float xv = ar[i][jj];
        const _Float16 h = (_Float16)xv;
        af[i][jj]     = h;
        af[i][jj + 4] = (_Float16)(xv - (float)h);
      }
    }
#pragma unroll
    for (int mi = 0; mi < 4; ++mi)
#pragma unroll
      for (int ni = 0; ni < 4; ++ni)
        acc[mi][ni] = __builtin_amdgcn_mfma_f32_16x16x32_f16(af[mi], bf[ni], acc[mi][ni], 0, 0, 0);
  }

  // epilogue: D layout col=lane&15, row=(lane>>4)*4+r + fused col stats; H fp32
  const int rq = (lane >> 4) * 4;
#pragma unroll
  for (int ni = 0; ni < 4; ++ni) {
    const int col = n0 + wn + ni * 16 + fr;
    const float a1 = alpha1[col];
    float s = 0.f, q = 0.f;
#pragma unroll
    for (int mi = 0; mi < 4; ++mi) {
#pragma unroll
      for (int r = 0; r < 4; ++r) {
        const int row = m0 + wm + mi * 16 + rq + r;
        const float v = acc[mi][ni][r] * a1;
        H[(long)row * H_DIM + col] = v;
        s += v;
        q += v * v;
      }
    }
    s += __shfl_xor(s, 16, 64);
    s += __shfl_xor(s, 32, 64);
    q += __shfl_xor(q, 16, 64);
    q += __shfl_xor(q, 32, 64);
    if ((lane >> 4) == 0) {
      atomicAdd(&colsum[col], s);
      atomicAdd(&colsumsq[col], q);
    }
  }
}

// ---------------------------------------------------------------------------
// K4: gemm2 — out[b][c] = sum_j sign(cs[j]*H[b][j]+ts[j]) * BW2h[c][j] via MFMA.
// 1024 blocks x 64 rows (wave: 16 rows, one acc chain). B staged in LDS;
// A-frags direct from global H (fp32) in MFMA A-layout, sign in-register.
// Quarter-waves {fr,fr+16,fr+32,fr+48} cover one full 128B line per row/instr.
// ---------------------------------------------------------------------------
__global__ __launch_bounds__(256) void gemm2(const float* __restrict__ H,
                                             const float* __restrict__ colsum,
                                             const float* __restrict__ colsumsq,
                                             const float* __restrict__ gamma,
                                             const float* __restrict__ beta,
                                             const _Float16* __restrict__ BW2h,
                                             float* __restrict__ out) {
  __shared__ float cs[H_DIM], ts[H_DIM];
  __shared__ _Float16 Bsh[CPAD * BROW];
  const int tid = threadIdx.x, lane = tid & 63, wave = tid >> 6;
  for (int j = tid; j < H_DIM; j += 256) {
    const float mu  = colsum[j] * (1.f / BATCH);
    const float var = colsumsq[j] * (1.f / BATCH) - mu * mu;
    const float c   = gamma[j] * rsqrtf(var + BN_EPS);
    cs[j] = c;
    ts[j] = beta[j] - c * mu;
  }
  for (int i = tid; i < CPAD * BROW / 8; i += 256)
    *(half8*)&Bsh[i * 8] = *(const half8*)&BW2h[i * 8];
  __syncthreads();

  // XCD-matched row mapping (H written XCD-major by gemm1)
  const int b    = blockIdx.x;                       // 1024 blocks
  const int row0 = (b & 7) * 8192 + (b >> 3) * 64;
  const int wrow = row0 + wave * 16;
  const int fr = lane & 15;
  const int kq = (lane >> 4) * 8;

  f32x4 acc = {};
  const float*    hp  = H + (long)(wrow + fr) * H_DIM + kq;
  const _Float16* bfp = &Bsh[fr * BROW + kq];

  for (int it = 0; it < H_DIM / 32; ++it) {
    const int k0 = it * 32;
    const half8 bf = *(const half8*)(bfp + k0);
    const f32x4 ha = *(const f32x4*)(hp + k0);
    const f32x4 hb = *(const f32x4*)(hp + k0 + 4);
    const f32x4 c0 = *(const f32x4*)&cs[k0 + kq];
    const f32x4 c1 = *(const f32x4*)&cs[k0 + kq + 4];
    const f32x4 t0 = *(const f32x4*)&ts[k0 + kq];
    const f32x4 t1 = *(const f32x4*)&ts[k0 + kq + 4];
    half8 a;
#pragma unroll
    for (int i = 0; i < 4; ++i) {
      a[i]     = (_Float16)signf(ha[i] * c0[i] + t0[i]);
      a[i + 4] = (_Float16)signf(hb[i] * c1[i] + t1[i]);
    }
    acc = __builtin_amdgcn_mfma_f32_16x16x32_f16(a, bf, acc, 0, 0, 0);
  }

  // D layout: col=lane&15 (=oc), row=(lane>>4)*4+r
  if (fr < C_DIM) {
    const int rb = (lane >> 4) * 4;
#pragma unroll
    for (int r = 0; r < 4; ++r)
      out[(long)(wrow + rb + r) * C_DIM + fr] = acc[r];
  }
}

// ---------------------------------------------------------------------------
extern "C" void kernel_launch(void* const* d_in, const int* in_sizes, int n_in,
                              void* d_out, int out_size, void* d_ws, size_t ws_size,
                              hipStream_t stream) {
  const float* x     = (const float*)d_in[0];
  const float* w1    = (const float*)d_in[1];
  const float* w2    = (const float*)d_in[2];
  const float* gamma = (const float*)d_in[3];
  const float* beta  = (const float*)d_in[4];
  float* out = (float*)d_out;

  char* ws = (char*)d_ws;
  float*    H      = (float*)  (ws + 0);             // 65536*1024*4 = 268,435,456
  _Float16* S2     = (_Float16*)(ws + 478150656LL);  // 1024*1600*2  =   3,276,800
  _Float16* BW2h   = (_Float16*)(ws + 481427456LL);  // 16*1032*2    =      33,024
  float*    ALPHA1 = (float*)  (ws + 481468416LL);   // 1024*4
  float*    COLS   = (float*)  (ws + 481472512LL);   // 1024*4
  float*    COLQ   = (float*)  (ws + 481476608LL);   // 1024*4

  hipMemsetAsync(COLS, 0, 2 * H_DIM * sizeof(float), stream);
  prep_w<<<H_DIM + CPAD, 256, 0, stream>>>(w1, w2, ALPHA1, S2, BW2h);
  gemm1<<<4096, 256, 0, stream>>>(x, S2, ALPHA1, H, COLS, COLQ);
  gemm2<<<1024, 256, 0, stream>>>(H, COLS, COLQ, gamma, beta, BW2h, out);
}